// Round 6
// baseline (91.785 us; speedup 1.0000x reference)
//
#include <hip/hip_runtime.h>

#define N_USER   100000
#define N_ITEM   200000
#define N_NODES  300000
#define NNZ      4000000
#define EMB      64
#define N_LAYERS 3
#define BATCH    4096
#define NSLOT    (3*BATCH)   // 12288
#define MAXE     96          // bucket capacity; edges/node ~ Poisson(13.3)
#define BMWORDS  9376        // ceil(300000/32) words = 37504 B

// ---------------- ws layout ----------------
// [0]         int   slot_of_node[N_NODES]   1,200,000 B (pad 1,200,128)
// [1200128]   int   count[NSLOT]            49,152 B
// [1249280]   int   csr_col[NSLOT*MAXE]     4,718,592 B
// [5967872]   float csr_val[NSLOT*MAXE]     4,718,592 B
// [10686464]  float side[NSLOT*EMB]         3,145,728 B
// [13832192]  uint  bitmap[BMWORDS]         37,504 B (pad 37,632)

__global__ void k_setup(const int* __restrict__ users,
                        const int* __restrict__ pos,
                        const int* __restrict__ neg,
                        int* __restrict__ slot_of_node,
                        int* __restrict__ count,
                        unsigned int* __restrict__ bitmap) {
    int i = blockIdx.x * blockDim.x + threadIdx.x;
    if (i >= NSLOT) return;
    count[i] = 0;
    int node;
    if (i < BATCH)            node = users[i];
    else if (i < 2 * BATCH)   node = N_USER + pos[i - BATCH];
    else                      node = N_USER + neg[i - 2 * BATCH];
    slot_of_node[node] = i;                   // benign race on duplicates (winner consistent)
    atomicOr(&bitmap[((unsigned)node) >> 5], 1u << (node & 31));
}

// stream row[] as int4; LDS-resident bitmap filters 96% of edges before any
// L2 gather. Hits: slot gather + bucket-fill (int atomic).
__global__ void __launch_bounds__(256) k_build(
        const int* __restrict__ row,
        const int* __restrict__ col,
        const float* __restrict__ vals,
        const int* __restrict__ slot_of_node,
        const unsigned int* __restrict__ bitmap,
        int* __restrict__ count,
        int* __restrict__ csr_col,
        float* __restrict__ csr_val) {
    __shared__ unsigned int bm[BMWORDS];
    int tid = threadIdx.x;
    {   // coalesced bitmap copy global->LDS (int4)
        const int4* src = (const int4*)bitmap;
        int4* dst = (int4*)bm;
        for (int i = tid; i < BMWORDS / 4; i += 256) dst[i] = src[i];
    }
    __syncthreads();

    const int4* rows4 = (const int4*)row;
    int gbase = blockIdx.x * 512;             // 512 int4s = 2048 edges per block
    #pragma unroll
    for (int q = 0; q < 2; ++q) {
        int t = gbase + q * 256 + tid;
        if (t < NNZ / 4) {
            int4 r = rows4[t];
            int e = t * 4;
            bool h0 = (bm[((unsigned)r.x) >> 5] >> (r.x & 31)) & 1;
            bool h1 = (bm[((unsigned)r.y) >> 5] >> (r.y & 31)) & 1;
            bool h2 = (bm[((unsigned)r.z) >> 5] >> (r.z & 31)) & 1;
            bool h3 = (bm[((unsigned)r.w) >> 5] >> (r.w & 31)) & 1;
            if (h0) { int s = slot_of_node[r.x]; int p = atomicAdd(&count[s], 1); if (p < MAXE) { csr_col[(size_t)s*MAXE+p] = col[e];   csr_val[(size_t)s*MAXE+p] = vals[e];   } }
            if (h1) { int s = slot_of_node[r.y]; int p = atomicAdd(&count[s], 1); if (p < MAXE) { csr_col[(size_t)s*MAXE+p] = col[e+1]; csr_val[(size_t)s*MAXE+p] = vals[e+1]; } }
            if (h2) { int s = slot_of_node[r.z]; int p = atomicAdd(&count[s], 1); if (p < MAXE) { csr_col[(size_t)s*MAXE+p] = col[e+2]; csr_val[(size_t)s*MAXE+p] = vals[e+2]; } }
            if (h3) { int s = slot_of_node[r.w]; int p = atomicAdd(&count[s], 1); if (p < MAXE) { csr_col[(size_t)s*MAXE+p] = col[e+3]; csr_val[(size_t)s*MAXE+p] = vals[e+3]; } }
        }
    }
}

// one wave per slot; 16-wide masked register gather -> side[]
__global__ void __launch_bounds__(256) k_gather(
        const int* __restrict__ users,
        const int* __restrict__ pos,
        const int* __restrict__ neg,
        const float* __restrict__ user_emb,
        const float* __restrict__ item_emb,
        const int* __restrict__ slot_of_node,
        const int* __restrict__ count,
        const int* __restrict__ csr_col,
        const float* __restrict__ csr_val,
        float* __restrict__ side) {
    int tid = threadIdx.x;
    int w = tid >> 6;
    int j = tid & 63;
    int slot = blockIdx.x * 4 + w;

    int node;
    if (slot < BATCH)          node = users[slot];
    else if (slot < 2 * BATCH) node = N_USER + pos[slot - BATCH];
    else                       node = N_USER + neg[slot - 2 * BATCH];

    int wslot = slot_of_node[node];               // winner slot (handles duplicates)
    wslot = __builtin_amdgcn_readfirstlane(wslot);
    int n = count[wslot];
    n = (n < MAXE) ? n : MAXE;
    n = __builtin_amdgcn_readfirstlane(n);
    const int*   cc = csr_col + (size_t)wslot * MAXE;
    const float* cv = csr_val + (size_t)wslot * MAXE;

    float acc = 0.f;
    for (int t0 = 0; t0 < n; t0 += 16) {          // masked rounds of 16 independent loads
        float vv[16];
        const float* ss[16];
        #pragma unroll
        for (int k = 0; k < 16; ++k) {
            int  t  = t0 + k;
            bool ok = t < n;
            int  idx = ok ? t : 0;                // n>=1 here, cc[0] valid
            int   c = cc[idx];
            float v = cv[idx];
            vv[k] = ok ? v : 0.f;
            ss[k] = (c < N_USER) ? (user_emb + (size_t)c * EMB)
                                 : (item_emb + (size_t)(c - N_USER) * EMB);
        }
        float gg[16];
        #pragma unroll
        for (int k = 0; k < 16; ++k) gg[k] = ss[k][j];
        #pragma unroll
        for (int k = 0; k < 16; ++k) acc = fmaf(vv[k], gg[k], acc);
    }
    side[(size_t)slot * EMB + j] = acc;
}

// 4 slots per wave, 16 per block; W staged in LDS per block per layer.
__global__ void __launch_bounds__(256) k_mlp(
        const int* __restrict__ users,
        const int* __restrict__ pos,
        const int* __restrict__ neg,
        const float* __restrict__ user_emb,
        const float* __restrict__ item_emb,
        const float* __restrict__ W_gc,
        const float* __restrict__ b_gc,
        const float* __restrict__ W_bi,
        const float* __restrict__ b_bi,
        const float* __restrict__ side,
        float* __restrict__ out) {
    __shared__ float wg[EMB * EMB];
    __shared__ float wb[EMB * EMB];
    int tid = threadIdx.x;
    int w = tid >> 6;
    int j = tid & 63;
    int sbase = blockIdx.x * 16 + w * 4;

    float sval[4], e[4];
    #pragma unroll
    for (int s = 0; s < 4; ++s) {
        int slot = sbase + s;
        int node;
        if (slot < BATCH)          node = users[slot];
        else if (slot < 2 * BATCH) node = N_USER + pos[slot - BATCH];
        else                       node = N_USER + neg[slot - 2 * BATCH];
        const float* erow = (node < N_USER) ? (user_emb + (size_t)node * EMB)
                                            : (item_emb + (size_t)(node - N_USER) * EMB);
        e[s]    = erow[j];
        sval[s] = side[(size_t)slot * EMB + j];
        out[(size_t)slot * 256 + j] = e[s];       // layer-0 columns: raw ego
    }

    for (int k = 0; k < N_LAYERS; ++k) {
        __syncthreads();                          // prev-layer LDS reads done
        {
            const float4* g4 = (const float4*)(W_gc + (size_t)k * EMB * EMB);
            const float4* b4 = (const float4*)(W_bi + (size_t)k * EMB * EMB);
            float4* lg = (float4*)wg;
            float4* lb = (float4*)wb;
            #pragma unroll
            for (int i2 = tid; i2 < EMB * EMB / 4; i2 += 256) { lg[i2] = g4[i2]; lb[i2] = b4[i2]; }
        }
        __syncthreads();                          // weights ready

        float b1 = b_gc[k * EMB + j];
        float b2 = b_bi[k * EMB + j];
        float sum1[4], sum2[4], pv[4];
        #pragma unroll
        for (int s = 0; s < 4; ++s) { sum1[s] = b1; sum2[s] = b2; pv[s] = sval[s] * e[s]; }

        #pragma unroll 8
        for (int i = 0; i < EMB; ++i) {
            float wgi = wg[i * EMB + j];
            float wbi = wb[i * EMB + j];
            #pragma unroll
            for (int s = 0; s < 4; ++s) {
                float si = __uint_as_float(__builtin_amdgcn_readlane(__float_as_uint(sval[s]), i));
                float pi = __uint_as_float(__builtin_amdgcn_readlane(__float_as_uint(pv[s]),   i));
                sum1[s] = fmaf(si, wgi, sum1[s]);
                sum2[s] = fmaf(pi, wbi, sum2[s]);
            }
        }

        #pragma unroll
        for (int s = 0; s < 4; ++s) {
            float x = sum1[s] + sum2[s];
            x = (x >= 0.f) ? x : 0.2f * x;        // leaky_relu 0.2
            float sq = x * x;                     // wave-wide L2 norm
            #pragma unroll
            for (int o = 32; o; o >>= 1) sq += __shfl_xor(sq, o, 64);
            float nn = fmaxf(sqrtf(sq), 1e-12f);
            out[(size_t)(sbase + s) * 256 + (k + 1) * 64 + j] = x / nn;
            e[s] = x;                             // next-layer ego = unnormalized output
        }
    }
}

extern "C" void kernel_launch(void* const* d_in, const int* in_sizes, int n_in,
                              void* d_out, int out_size, void* d_ws, size_t ws_size,
                              hipStream_t stream) {
    const int*   users    = (const int*)  d_in[0];
    const int*   pos      = (const int*)  d_in[1];
    const int*   neg      = (const int*)  d_in[2];
    const int*   row      = (const int*)  d_in[3];
    const int*   col      = (const int*)  d_in[4];
    const float* vals     = (const float*)d_in[5];
    const float* user_emb = (const float*)d_in[6];
    const float* item_emb = (const float*)d_in[7];
    const float* W_gc     = (const float*)d_in[8];
    const float* b_gc     = (const float*)d_in[9];
    const float* W_bi     = (const float*)d_in[10];
    const float* b_bi     = (const float*)d_in[11];
    float* out = (float*)d_out;

    char* ws = (char*)d_ws;
    int*          slot_of_node = (int*)ws;
    int*          count        = (int*)(ws + 1200128);
    int*          csr_col      = (int*)(ws + 1249280);
    float*        csr_val      = (float*)(ws + 5967872);
    float*        side         = (float*)(ws + 10686464);
    unsigned int* bitmap       = (unsigned int*)(ws + 13832192);

    hipMemsetAsync(slot_of_node, 0xFF, (size_t)N_NODES * sizeof(int), stream);
    hipMemsetAsync(bitmap, 0, (size_t)BMWORDS * sizeof(unsigned int), stream);

    k_setup<<<(NSLOT + 255) / 256, 256, 0, stream>>>(users, pos, neg,
                                                     slot_of_node, count, bitmap);
    k_build<<<(NNZ / 4 + 511) / 512, 256, 0, stream>>>(row, col, vals, slot_of_node,
                                                       bitmap, count, csr_col, csr_val);
    k_gather<<<NSLOT / 4, 256, 0, stream>>>(users, pos, neg, user_emb, item_emb,
                                            slot_of_node, count, csr_col, csr_val,
                                            side);
    k_mlp<<<NSLOT / 16, 256, 0, stream>>>(users, pos, neg, user_emb, item_emb,
                                          W_gc, b_gc, W_bi, b_bi, side, out);
}

// Round 7
// 88.833 us; speedup vs baseline: 1.0332x; 1.0332x over previous
//
#include <hip/hip_runtime.h>

#define N_USER   100000
#define N_ITEM   200000
#define N_NODES  300000
#define NNZ      4000000
#define EMB      64
#define N_LAYERS 3
#define BATCH    4096
#define NSLOT    (3*BATCH)   // 12288
#define MAXE     96          // bucket capacity; edges/node ~ Poisson(13.3)
#define HCAP     768         // LDS hit buffer; hits/block ~ N(163, 12.5) -> 48 sigma

// ---------------- ws layout ----------------
// [0]         int   slot_of_node[N_NODES]   1,200,000 B (pad 1,200,128)
// [1200128]   int   count[NSLOT]            49,152 B
// [1249280]   int   csr_col[NSLOT*MAXE]     4,718,592 B
// [5967872]   float csr_val[NSLOT*MAXE]     4,718,592 B
// [10686464]  float side[NSLOT*EMB]         3,145,728 B

__global__ void k_setup(const int* __restrict__ users,
                        const int* __restrict__ pos,
                        const int* __restrict__ neg,
                        int* __restrict__ slot_of_node,
                        int* __restrict__ count) {
    int i = blockIdx.x * blockDim.x + threadIdx.x;
    if (i >= NSLOT) return;
    count[i] = 0;
    int node;
    if (i < BATCH)            node = users[i];
    else if (i < 2 * BATCH)   node = N_USER + pos[i - BATCH];
    else                      node = N_USER + neg[i - 2 * BATCH];
    slot_of_node[node] = i;                   // benign race on duplicates (winner consistent)
}

// compact-then-process: phase A streams rows + slot gathers (16 in flight),
// compacts hits into LDS; phase B processes hits wave-dense.
__global__ void __launch_bounds__(256) k_build(
        const int* __restrict__ row,
        const int* __restrict__ col,
        const float* __restrict__ vals,
        const int* __restrict__ slot_of_node,
        int* __restrict__ count,
        int* __restrict__ csr_col,
        float* __restrict__ csr_val) {
    __shared__ int ls_e[HCAP];
    __shared__ int ls_s[HCAP];
    __shared__ int cnt;
    int tid = threadIdx.x;
    if (tid == 0) cnt = 0;
    __syncthreads();

    const int4* rows4 = (const int4*)row;
    const int nt4 = NNZ / 4;
    int base4 = blockIdx.x * 1024;            // 1024 int4 = 4096 edges per block

    // phase A: load 4 int4 rows, then 16 independent slot gathers, then compact
    int4 r[4]; bool ok[4];
    #pragma unroll
    for (int q = 0; q < 4; ++q) {
        int t = base4 + q * 256 + tid;
        ok[q] = t < nt4;
        r[q] = rows4[ok[q] ? t : 0];
    }
    int s[16];
    #pragma unroll
    for (int q = 0; q < 4; ++q) {
        s[q * 4 + 0] = slot_of_node[r[q].x];
        s[q * 4 + 1] = slot_of_node[r[q].y];
        s[q * 4 + 2] = slot_of_node[r[q].z];
        s[q * 4 + 3] = slot_of_node[r[q].w];
    }
    #pragma unroll
    for (int q = 0; q < 4; ++q) {
        if (!ok[q]) continue;
        int e = (base4 + q * 256 + tid) * 4;
        #pragma unroll
        for (int i = 0; i < 4; ++i) {
            int si = s[q * 4 + i];
            if (si >= 0) {
                int p = atomicAdd(&cnt, 1);   // LDS atomic
                if (p < HCAP) { ls_e[p] = e + i; ls_s[p] = si; }
                else {                        // overflow fallback (practically never)
                    int pp = atomicAdd(&count[si], 1);
                    if (pp < MAXE) {
                        csr_col[(size_t)si * MAXE + pp] = col[e + i];
                        csr_val[(size_t)si * MAXE + pp] = vals[e + i];
                    }
                }
            }
        }
    }
    __syncthreads();

    // phase B: wave-dense hit processing (64 hits per memory instruction)
    int n = cnt; n = (n < HCAP) ? n : HCAP;
    for (int t = tid; t < n; t += 256) {
        int e  = ls_e[t];
        int si = ls_s[t];
        int c  = col[e];
        float v = vals[e];
        int p = atomicAdd(&count[si], 1);
        if (p < MAXE) {
            csr_col[(size_t)si * MAXE + p] = c;
            csr_val[(size_t)si * MAXE + p] = v;
        }
    }
}

// one wave per slot; 16-wide masked register gather -> side[]
__global__ void __launch_bounds__(256) k_gather(
        const int* __restrict__ users,
        const int* __restrict__ pos,
        const int* __restrict__ neg,
        const float* __restrict__ user_emb,
        const float* __restrict__ item_emb,
        const int* __restrict__ slot_of_node,
        const int* __restrict__ count,
        const int* __restrict__ csr_col,
        const float* __restrict__ csr_val,
        float* __restrict__ side) {
    int tid = threadIdx.x;
    int w = tid >> 6;
    int j = tid & 63;
    int slot = blockIdx.x * 4 + w;

    int node;
    if (slot < BATCH)          node = users[slot];
    else if (slot < 2 * BATCH) node = N_USER + pos[slot - BATCH];
    else                       node = N_USER + neg[slot - 2 * BATCH];

    int wslot = slot_of_node[node];               // winner slot (handles duplicates)
    wslot = __builtin_amdgcn_readfirstlane(wslot);
    int n = count[wslot];
    n = (n < MAXE) ? n : MAXE;
    n = __builtin_amdgcn_readfirstlane(n);
    const int*   cc = csr_col + (size_t)wslot * MAXE;
    const float* cv = csr_val + (size_t)wslot * MAXE;

    float acc = 0.f;
    for (int t0 = 0; t0 < n; t0 += 16) {          // masked rounds of 16 independent loads
        float vv[16];
        const float* ss[16];
        #pragma unroll
        for (int k = 0; k < 16; ++k) {
            int  t  = t0 + k;
            bool okk = t < n;
            int  idx = okk ? t : 0;               // n>=1 here, cc[0] valid
            int   c = cc[idx];
            float v = cv[idx];
            vv[k] = okk ? v : 0.f;
            ss[k] = (c < N_USER) ? (user_emb + (size_t)c * EMB)
                                 : (item_emb + (size_t)(c - N_USER) * EMB);
        }
        float gg[16];
        #pragma unroll
        for (int k = 0; k < 16; ++k) gg[k] = ss[k][j];
        #pragma unroll
        for (int k = 0; k < 16; ++k) acc = fmaf(vv[k], gg[k], acc);
    }
    side[(size_t)slot * EMB + j] = acc;
}

// 4 slots per wave, 16 per block; W staged in LDS per block per layer.
__global__ void __launch_bounds__(256) k_mlp(
        const int* __restrict__ users,
        const int* __restrict__ pos,
        const int* __restrict__ neg,
        const float* __restrict__ user_emb,
        const float* __restrict__ item_emb,
        const float* __restrict__ W_gc,
        const float* __restrict__ b_gc,
        const float* __restrict__ W_bi,
        const float* __restrict__ b_bi,
        const float* __restrict__ side,
        float* __restrict__ out) {
    __shared__ float wg[EMB * EMB];
    __shared__ float wb[EMB * EMB];
    int tid = threadIdx.x;
    int w = tid >> 6;
    int j = tid & 63;
    int sbase = blockIdx.x * 16 + w * 4;

    float sval[4], e[4];
    #pragma unroll
    for (int s = 0; s < 4; ++s) {
        int slot = sbase + s;
        int node;
        if (slot < BATCH)          node = users[slot];
        else if (slot < 2 * BATCH) node = N_USER + pos[slot - BATCH];
        else                       node = N_USER + neg[slot - 2 * BATCH];
        const float* erow = (node < N_USER) ? (user_emb + (size_t)node * EMB)
                                            : (item_emb + (size_t)(node - N_USER) * EMB);
        e[s]    = erow[j];
        sval[s] = side[(size_t)slot * EMB + j];
        out[(size_t)slot * 256 + j] = e[s];       // layer-0 columns: raw ego
    }

    for (int k = 0; k < N_LAYERS; ++k) {
        __syncthreads();                          // prev-layer LDS reads done
        {
            const float4* g4 = (const float4*)(W_gc + (size_t)k * EMB * EMB);
            const float4* b4 = (const float4*)(W_bi + (size_t)k * EMB * EMB);
            float4* lg = (float4*)wg;
            float4* lb = (float4*)wb;
            #pragma unroll
            for (int i2 = tid; i2 < EMB * EMB / 4; i2 += 256) { lg[i2] = g4[i2]; lb[i2] = b4[i2]; }
        }
        __syncthreads();                          // weights ready

        float b1 = b_gc[k * EMB + j];
        float b2 = b_bi[k * EMB + j];
        float sum1[4], sum2[4], pv[4];
        #pragma unroll
        for (int s = 0; s < 4; ++s) { sum1[s] = b1; sum2[s] = b2; pv[s] = sval[s] * e[s]; }

        #pragma unroll 8
        for (int i = 0; i < EMB; ++i) {
            float wgi = wg[i * EMB + j];
            float wbi = wb[i * EMB + j];
            #pragma unroll
            for (int s = 0; s < 4; ++s) {
                float si = __uint_as_float(__builtin_amdgcn_readlane(__float_as_uint(sval[s]), i));
                float pi = __uint_as_float(__builtin_amdgcn_readlane(__float_as_uint(pv[s]),   i));
                sum1[s] = fmaf(si, wgi, sum1[s]);
                sum2[s] = fmaf(pi, wbi, sum2[s]);
            }
        }

        #pragma unroll
        for (int s = 0; s < 4; ++s) {
            float x = sum1[s] + sum2[s];
            x = (x >= 0.f) ? x : 0.2f * x;        // leaky_relu 0.2
            float sq = x * x;                     // wave-wide L2 norm
            #pragma unroll
            for (int o = 32; o; o >>= 1) sq += __shfl_xor(sq, o, 64);
            float nn = fmaxf(sqrtf(sq), 1e-12f);
            out[(size_t)(sbase + s) * 256 + (k + 1) * 64 + j] = x / nn;
            e[s] = x;                             // next-layer ego = unnormalized output
        }
    }
}

extern "C" void kernel_launch(void* const* d_in, const int* in_sizes, int n_in,
                              void* d_out, int out_size, void* d_ws, size_t ws_size,
                              hipStream_t stream) {
    const int*   users    = (const int*)  d_in[0];
    const int*   pos      = (const int*)  d_in[1];
    const int*   neg      = (const int*)  d_in[2];
    const int*   row      = (const int*)  d_in[3];
    const int*   col      = (const int*)  d_in[4];
    const float* vals     = (const float*)d_in[5];
    const float* user_emb = (const float*)d_in[6];
    const float* item_emb = (const float*)d_in[7];
    const float* W_gc     = (const float*)d_in[8];
    const float* b_gc     = (const float*)d_in[9];
    const float* W_bi     = (const float*)d_in[10];
    const float* b_bi     = (const float*)d_in[11];
    float* out = (float*)d_out;

    char* ws = (char*)d_ws;
    int*   slot_of_node = (int*)ws;
    int*   count        = (int*)(ws + 1200128);
    int*   csr_col      = (int*)(ws + 1249280);
    float* csr_val      = (float*)(ws + 5967872);
    float* side         = (float*)(ws + 10686464);

    hipMemsetAsync(slot_of_node, 0xFF, (size_t)N_NODES * sizeof(int), stream);

    k_setup<<<(NSLOT + 255) / 256, 256, 0, stream>>>(users, pos, neg,
                                                     slot_of_node, count);
    k_build<<<(NNZ / 4 + 1023) / 1024, 256, 0, stream>>>(row, col, vals, slot_of_node,
                                                         count, csr_col, csr_val);
    k_gather<<<NSLOT / 4, 256, 0, stream>>>(users, pos, neg, user_emb, item_emb,
                                            slot_of_node, count, csr_col, csr_val,
                                            side);
    k_mlp<<<NSLOT / 16, 256, 0, stream>>>(users, pos, neg, user_emb, item_emb,
                                          W_gc, b_gc, W_bi, b_bi, side, out);
}

// Round 8
// 88.428 us; speedup vs baseline: 1.0380x; 1.0046x over previous
//
#include <hip/hip_runtime.h>

#define N_USER   100000
#define N_ITEM   200000
#define N_NODES  300000
#define NNZ      4000000
#define EMB      64
#define N_LAYERS 3
#define BATCH    4096
#define NSLOT    (3*BATCH)   // 12288
#define MAXE     96          // bucket capacity; edges/node ~ Poisson(13.3)
#define HCAP     768         // LDS hit buffer; hits/block ~ N(163, 12.5) -> 48 sigma
#define NWORD4   75000       // 300000 ints / 4 per int4

// ---------------- ws layout ----------------
// [0]         int   slot_of_node[N_NODES]   1,200,000 B (pad 1,200,128)
// [1200128]   int   count[NSLOT]            49,152 B
// [1249280]   int   csr_col[NSLOT*MAXE]     4,718,592 B
// [5967872]   float csr_val[NSLOT*MAXE]     4,718,592 B
// [10686464]  float side[NSLOT*EMB]         3,145,728 B

// custom clear: rocclr's fillBufferAligned runs at 28 GB/s for 1.2 MB (R7 profile);
// a plain int4 store stream does the same work in ~3 us.
__global__ void __launch_bounds__(256) k_clear(int4* __restrict__ p) {
    int i = blockIdx.x * blockDim.x + threadIdx.x;
    if (i < NWORD4) p[i] = make_int4(-1, -1, -1, -1);
}

__global__ void k_setup(const int* __restrict__ users,
                        const int* __restrict__ pos,
                        const int* __restrict__ neg,
                        int* __restrict__ slot_of_node,
                        int* __restrict__ count) {
    int i = blockIdx.x * blockDim.x + threadIdx.x;
    if (i >= NSLOT) return;
    count[i] = 0;
    int node;
    if (i < BATCH)            node = users[i];
    else if (i < 2 * BATCH)   node = N_USER + pos[i - BATCH];
    else                      node = N_USER + neg[i - 2 * BATCH];
    slot_of_node[node] = i;                   // benign race on duplicates (winner consistent)
}

// compact-then-process: phase A streams rows + slot gathers (16 in flight),
// compacts hits into LDS; phase B processes hits wave-dense.
__global__ void __launch_bounds__(256) k_build(
        const int* __restrict__ row,
        const int* __restrict__ col,
        const float* __restrict__ vals,
        const int* __restrict__ slot_of_node,
        int* __restrict__ count,
        int* __restrict__ csr_col,
        float* __restrict__ csr_val) {
    __shared__ int ls_e[HCAP];
    __shared__ int ls_s[HCAP];
    __shared__ int cnt;
    int tid = threadIdx.x;
    if (tid == 0) cnt = 0;
    __syncthreads();

    const int4* rows4 = (const int4*)row;
    const int nt4 = NNZ / 4;
    int base4 = blockIdx.x * 1024;            // 1024 int4 = 4096 edges per block

    // phase A: load 4 int4 rows, then 16 independent slot gathers, then compact
    int4 r[4]; bool ok[4];
    #pragma unroll
    for (int q = 0; q < 4; ++q) {
        int t = base4 + q * 256 + tid;
        ok[q] = t < nt4;
        r[q] = rows4[ok[q] ? t : 0];
    }
    int s[16];
    #pragma unroll
    for (int q = 0; q < 4; ++q) {
        s[q * 4 + 0] = slot_of_node[r[q].x];
        s[q * 4 + 1] = slot_of_node[r[q].y];
        s[q * 4 + 2] = slot_of_node[r[q].z];
        s[q * 4 + 3] = slot_of_node[r[q].w];
    }
    #pragma unroll
    for (int q = 0; q < 4; ++q) {
        if (!ok[q]) continue;
        int e = (base4 + q * 256 + tid) * 4;
        #pragma unroll
        for (int i = 0; i < 4; ++i) {
            int si = s[q * 4 + i];
            if (si >= 0) {
                int p = atomicAdd(&cnt, 1);   // LDS atomic
                if (p < HCAP) { ls_e[p] = e + i; ls_s[p] = si; }
                else {                        // overflow fallback (practically never)
                    int pp = atomicAdd(&count[si], 1);
                    if (pp < MAXE) {
                        csr_col[(size_t)si * MAXE + pp] = col[e + i];
                        csr_val[(size_t)si * MAXE + pp] = vals[e + i];
                    }
                }
            }
        }
    }
    __syncthreads();

    // phase B: wave-dense hit processing (64 hits per memory instruction)
    int n = cnt; n = (n < HCAP) ? n : HCAP;
    for (int t = tid; t < n; t += 256) {
        int e  = ls_e[t];
        int si = ls_s[t];
        int c  = col[e];
        float v = vals[e];
        int p = atomicAdd(&count[si], 1);
        if (p < MAXE) {
            csr_col[(size_t)si * MAXE + p] = c;
            csr_val[(size_t)si * MAXE + p] = v;
        }
    }
}

// one wave per slot; 16-wide masked register gather -> side[]
__global__ void __launch_bounds__(256) k_gather(
        const int* __restrict__ users,
        const int* __restrict__ pos,
        const int* __restrict__ neg,
        const float* __restrict__ user_emb,
        const float* __restrict__ item_emb,
        const int* __restrict__ slot_of_node,
        const int* __restrict__ count,
        const int* __restrict__ csr_col,
        const float* __restrict__ csr_val,
        float* __restrict__ side) {
    int tid = threadIdx.x;
    int w = tid >> 6;
    int j = tid & 63;
    int slot = blockIdx.x * 4 + w;

    int node;
    if (slot < BATCH)          node = users[slot];
    else if (slot < 2 * BATCH) node = N_USER + pos[slot - BATCH];
    else                       node = N_USER + neg[slot - 2 * BATCH];

    int wslot = slot_of_node[node];               // winner slot (handles duplicates)
    wslot = __builtin_amdgcn_readfirstlane(wslot);
    int n = count[wslot];
    n = (n < MAXE) ? n : MAXE;
    n = __builtin_amdgcn_readfirstlane(n);
    const int*   cc = csr_col + (size_t)wslot * MAXE;
    const float* cv = csr_val + (size_t)wslot * MAXE;

    float acc = 0.f;
    for (int t0 = 0; t0 < n; t0 += 16) {          // masked rounds of 16 independent loads
        float vv[16];
        const float* ss[16];
        #pragma unroll
        for (int k = 0; k < 16; ++k) {
            int  t  = t0 + k;
            bool okk = t < n;
            int  idx = okk ? t : 0;               // n>=1 here, cc[0] valid
            int   c = cc[idx];
            float v = cv[idx];
            vv[k] = okk ? v : 0.f;
            ss[k] = (c < N_USER) ? (user_emb + (size_t)c * EMB)
                                 : (item_emb + (size_t)(c - N_USER) * EMB);
        }
        float gg[16];
        #pragma unroll
        for (int k = 0; k < 16; ++k) gg[k] = ss[k][j];
        #pragma unroll
        for (int k = 0; k < 16; ++k) acc = fmaf(vv[k], gg[k], acc);
    }
    side[(size_t)slot * EMB + j] = acc;
}

// 4 slots per wave, 16 per block; W staged in LDS per block per layer.
__global__ void __launch_bounds__(256) k_mlp(
        const int* __restrict__ users,
        const int* __restrict__ pos,
        const int* __restrict__ neg,
        const float* __restrict__ user_emb,
        const float* __restrict__ item_emb,
        const float* __restrict__ W_gc,
        const float* __restrict__ b_gc,
        const float* __restrict__ W_bi,
        const float* __restrict__ b_bi,
        const float* __restrict__ side,
        float* __restrict__ out) {
    __shared__ float wg[EMB * EMB];
    __shared__ float wb[EMB * EMB];
    int tid = threadIdx.x;
    int w = tid >> 6;
    int j = tid & 63;
    int sbase = blockIdx.x * 16 + w * 4;

    float sval[4], e[4];
    #pragma unroll
    for (int s = 0; s < 4; ++s) {
        int slot = sbase + s;
        int node;
        if (slot < BATCH)          node = users[slot];
        else if (slot < 2 * BATCH) node = N_USER + pos[slot - BATCH];
        else                       node = N_USER + neg[slot - 2 * BATCH];
        const float* erow = (node < N_USER) ? (user_emb + (size_t)node * EMB)
                                            : (item_emb + (size_t)(node - N_USER) * EMB);
        e[s]    = erow[j];
        sval[s] = side[(size_t)slot * EMB + j];
        out[(size_t)slot * 256 + j] = e[s];       // layer-0 columns: raw ego
    }

    for (int k = 0; k < N_LAYERS; ++k) {
        __syncthreads();                          // prev-layer LDS reads done
        {
            const float4* g4 = (const float4*)(W_gc + (size_t)k * EMB * EMB);
            const float4* b4 = (const float4*)(W_bi + (size_t)k * EMB * EMB);
            float4* lg = (float4*)wg;
            float4* lb = (float4*)wb;
            #pragma unroll
            for (int i2 = tid; i2 < EMB * EMB / 4; i2 += 256) { lg[i2] = g4[i2]; lb[i2] = b4[i2]; }
        }
        __syncthreads();                          // weights ready

        float b1 = b_gc[k * EMB + j];
        float b2 = b_bi[k * EMB + j];
        float sum1[4], sum2[4], pv[4];
        #pragma unroll
        for (int s = 0; s < 4; ++s) { sum1[s] = b1; sum2[s] = b2; pv[s] = sval[s] * e[s]; }

        #pragma unroll 8
        for (int i = 0; i < EMB; ++i) {
            float wgi = wg[i * EMB + j];
            float wbi = wb[i * EMB + j];
            #pragma unroll
            for (int s = 0; s < 4; ++s) {
                float si = __uint_as_float(__builtin_amdgcn_readlane(__float_as_uint(sval[s]), i));
                float pi = __uint_as_float(__builtin_amdgcn_readlane(__float_as_uint(pv[s]),   i));
                sum1[s] = fmaf(si, wgi, sum1[s]);
                sum2[s] = fmaf(pi, wbi, sum2[s]);
            }
        }

        #pragma unroll
        for (int s = 0; s < 4; ++s) {
            float x = sum1[s] + sum2[s];
            x = (x >= 0.f) ? x : 0.2f * x;        // leaky_relu 0.2
            float sq = x * x;                     // wave-wide L2 norm
            #pragma unroll
            for (int o = 32; o; o >>= 1) sq += __shfl_xor(sq, o, 64);
            float nn = fmaxf(sqrtf(sq), 1e-12f);
            out[(size_t)(sbase + s) * 256 + (k + 1) * 64 + j] = x / nn;
            e[s] = x;                             // next-layer ego = unnormalized output
        }
    }
}

extern "C" void kernel_launch(void* const* d_in, const int* in_sizes, int n_in,
                              void* d_out, int out_size, void* d_ws, size_t ws_size,
                              hipStream_t stream) {
    const int*   users    = (const int*)  d_in[0];
    const int*   pos      = (const int*)  d_in[1];
    const int*   neg      = (const int*)  d_in[2];
    const int*   row      = (const int*)  d_in[3];
    const int*   col      = (const int*)  d_in[4];
    const float* vals     = (const float*)d_in[5];
    const float* user_emb = (const float*)d_in[6];
    const float* item_emb = (const float*)d_in[7];
    const float* W_gc     = (const float*)d_in[8];
    const float* b_gc     = (const float*)d_in[9];
    const float* W_bi     = (const float*)d_in[10];
    const float* b_bi     = (const float*)d_in[11];
    float* out = (float*)d_out;

    char* ws = (char*)d_ws;
    int*   slot_of_node = (int*)ws;
    int*   count        = (int*)(ws + 1200128);
    int*   csr_col      = (int*)(ws + 1249280);
    float* csr_val      = (float*)(ws + 5967872);
    float* side         = (float*)(ws + 10686464);

    k_clear<<<(NWORD4 + 255) / 256, 256, 0, stream>>>((int4*)slot_of_node);
    k_setup<<<(NSLOT + 255) / 256, 256, 0, stream>>>(users, pos, neg,
                                                     slot_of_node, count);
    k_build<<<(NNZ / 4 + 1023) / 1024, 256, 0, stream>>>(row, col, vals, slot_of_node,
                                                         count, csr_col, csr_val);
    k_gather<<<NSLOT / 4, 256, 0, stream>>>(users, pos, neg, user_emb, item_emb,
                                            slot_of_node, count, csr_col, csr_val,
                                            side);
    k_mlp<<<NSLOT / 16, 256, 0, stream>>>(users, pos, neg, user_emb, item_emb,
                                          W_gc, b_gc, W_bi, b_bi, side, out);
}

// Round 9
// 81.867 us; speedup vs baseline: 1.1212x; 1.0801x over previous
//
#include <hip/hip_runtime.h>

#define N_USER   100000
#define N_ITEM   200000
#define N_NODES  300000
#define NNZ      4000000
#define EMB      64
#define N_LAYERS 3
#define BATCH    4096
#define NSLOT    (3*BATCH)   // 12288
#define MAXE     96          // bucket capacity; edges/node ~ Poisson(13.3)
#define HCAP     768         // LDS hit buffer; hits/block ~ N(84, 9) -> 76 sigma

// ---------------- ws layout ----------------
// [0]         u16  table16[N_NODES]       600,000 B (pad 600,064)
// [600064]    int  count[NSLOT]           49,152 B
// [649216]    int2 csr2[NSLOT*MAXE]       9,437,184 B   (col, val-bits interleaved)
// [10086400]  float side[NSLOT*EMB]       3,145,728 B

#define TBL4   37500     // 600,000 B / 16
#define CNT4   3072      // 49,152 B / 16

// clears table16 (-1) and count (0) in one streaming kernel
__global__ void __launch_bounds__(256) k_clear(int4* __restrict__ table4,
                                               int4* __restrict__ count4) {
    int i = blockIdx.x * blockDim.x + threadIdx.x;
    if (i < TBL4)              table4[i] = make_int4(-1, -1, -1, -1);
    else if (i < TBL4 + CNT4)  count4[i - TBL4] = make_int4(0, 0, 0, 0);
}

__global__ void k_setup(const int* __restrict__ users,
                        const int* __restrict__ pos,
                        const int* __restrict__ neg,
                        unsigned short* __restrict__ table16) {
    int i = blockIdx.x * blockDim.x + threadIdx.x;
    if (i >= NSLOT) return;
    int node;
    if (i < BATCH)            node = users[i];
    else if (i < 2 * BATCH)   node = N_USER + pos[i - BATCH];
    else                      node = N_USER + neg[i - 2 * BATCH];
    table16[node] = (unsigned short)i;        // benign race on duplicates (winner consistent)
}

// stream row+col+vals coalesced (48 MB); LDS-compact hits carrying (slot,col,val);
// phase B: one count atomic + one int2 store per hit. No scattered input gathers.
__global__ void __launch_bounds__(256) k_build(
        const int* __restrict__ row,
        const int* __restrict__ col,
        const float* __restrict__ vals,
        const unsigned short* __restrict__ table16,
        int* __restrict__ count,
        int2* __restrict__ csr2) {
    __shared__ int   ls_s[HCAP];
    __shared__ int   ls_c[HCAP];
    __shared__ float ls_v[HCAP];
    __shared__ int   cnt;
    int tid = threadIdx.x;
    if (tid == 0) cnt = 0;
    __syncthreads();

    const int4*   rows4 = (const int4*)row;
    const int4*   cols4 = (const int4*)col;
    const float4* vals4 = (const float4*)vals;
    const int nt4 = NNZ / 4;                  // 1,000,000
    int base4 = blockIdx.x * 512;             // 512 int4 = 2048 edges per block

    int4 r[2], c[2]; float4 v[2]; bool ok[2];
    #pragma unroll
    for (int q = 0; q < 2; ++q) {
        int t = base4 + q * 256 + tid;
        ok[q] = t < nt4;
        int tt = ok[q] ? t : 0;
        r[q] = rows4[tt];
        c[q] = cols4[tt];
        v[q] = vals4[tt];
    }
    int s[8];
    #pragma unroll
    for (int q = 0; q < 2; ++q) {
        s[q * 4 + 0] = (int)(short)table16[r[q].x];
        s[q * 4 + 1] = (int)(short)table16[r[q].y];
        s[q * 4 + 2] = (int)(short)table16[r[q].z];
        s[q * 4 + 3] = (int)(short)table16[r[q].w];
    }
    #pragma unroll
    for (int q = 0; q < 2; ++q) {
        if (!ok[q]) continue;
        int cc[4] = { c[q].x, c[q].y, c[q].z, c[q].w };
        float vv[4] = { v[q].x, v[q].y, v[q].z, v[q].w };
        #pragma unroll
        for (int i = 0; i < 4; ++i) {
            int si = s[q * 4 + i];
            if (si >= 0) {
                int p = atomicAdd(&cnt, 1);   // LDS atomic
                if (p < HCAP) { ls_s[p] = si; ls_c[p] = cc[i]; ls_v[p] = vv[i]; }
                else {                        // overflow fallback (practically never)
                    int pp = atomicAdd(&count[si], 1);
                    if (pp < MAXE)
                        csr2[(size_t)si * MAXE + pp] = make_int2(cc[i], __float_as_int(vv[i]));
                }
            }
        }
    }
    __syncthreads();

    // phase B: wave-dense: one atomic + one 8B store per hit
    int n = cnt; n = (n < HCAP) ? n : HCAP;
    for (int t = tid; t < n; t += 256) {
        int si = ls_s[t];
        int p = atomicAdd(&count[si], 1);
        if (p < MAXE)
            csr2[(size_t)si * MAXE + p] = make_int2(ls_c[t], __float_as_int(ls_v[t]));
    }
}

// one wave per slot; lane-parallel edge load + shfl broadcast; 16-wide gather rounds.
__global__ void __launch_bounds__(256) k_gather(
        const int* __restrict__ users,
        const int* __restrict__ pos,
        const int* __restrict__ neg,
        const float* __restrict__ user_emb,
        const float* __restrict__ item_emb,
        const unsigned short* __restrict__ table16,
        const int* __restrict__ count,
        const int2* __restrict__ csr2,
        float* __restrict__ side) {
    int tid = threadIdx.x;
    int w = tid >> 6;
    int j = tid & 63;
    int slot = blockIdx.x * 4 + w;

    int node;
    if (slot < BATCH)          node = users[slot];
    else if (slot < 2 * BATCH) node = N_USER + pos[slot - BATCH];
    else                       node = N_USER + neg[slot - 2 * BATCH];

    int wslot = (int)(short)table16[node];        // winner slot (handles duplicates)
    wslot = __builtin_amdgcn_readfirstlane(wslot);
    int n = count[wslot];
    n = (n < MAXE) ? n : MAXE;
    n = __builtin_amdgcn_readfirstlane(n);
    const int2* base = csr2 + (size_t)wslot * MAXE;

    float acc = 0.f;
    for (int t0 = 0; t0 < n; t0 += 64) {
        int idx = t0 + j;
        int2 ev = make_int2(0, 0);
        if (idx < n) ev = base[idx];              // lane j holds edge t0+j
        int m = n - t0; m = (m < 64) ? m : 64;
        for (int tt = 0; tt < m; tt += 16) {
            float vv[16], gg[16];
            #pragma unroll
            for (int k = 0; k < 16; ++k) {
                int  t  = tt + k;
                bool okk = t < m;
                int   cc = __shfl(ev.x, t, 64);
                float vb = __uint_as_float((unsigned)__shfl(ev.y, t, 64));
                vv[k] = okk ? vb : 0.f;
                int ci = okk ? cc : 0;
                const float* sp = (ci < N_USER) ? (user_emb + (size_t)ci * EMB)
                                                : (item_emb + (size_t)(ci - N_USER) * EMB);
                gg[k] = sp[j];
            }
            #pragma unroll
            for (int k = 0; k < 16; ++k) acc = fmaf(vv[k], gg[k], acc);
        }
    }
    side[(size_t)slot * EMB + j] = acc;
}

// 4 slots per wave, 16 per block; W staged in LDS per block per layer.
__global__ void __launch_bounds__(256) k_mlp(
        const int* __restrict__ users,
        const int* __restrict__ pos,
        const int* __restrict__ neg,
        const float* __restrict__ user_emb,
        const float* __restrict__ item_emb,
        const float* __restrict__ W_gc,
        const float* __restrict__ b_gc,
        const float* __restrict__ W_bi,
        const float* __restrict__ b_bi,
        const float* __restrict__ side,
        float* __restrict__ out) {
    __shared__ float wg[EMB * EMB];
    __shared__ float wb[EMB * EMB];
    int tid = threadIdx.x;
    int w = tid >> 6;
    int j = tid & 63;
    int sbase = blockIdx.x * 16 + w * 4;

    float sval[4], e[4];
    #pragma unroll
    for (int s = 0; s < 4; ++s) {
        int slot = sbase + s;
        int node;
        if (slot < BATCH)          node = users[slot];
        else if (slot < 2 * BATCH) node = N_USER + pos[slot - BATCH];
        else                       node = N_USER + neg[slot - 2 * BATCH];
        const float* erow = (node < N_USER) ? (user_emb + (size_t)node * EMB)
                                            : (item_emb + (size_t)(node - N_USER) * EMB);
        e[s]    = erow[j];
        sval[s] = side[(size_t)slot * EMB + j];
        out[(size_t)slot * 256 + j] = e[s];       // layer-0 columns: raw ego
    }

    for (int k = 0; k < N_LAYERS; ++k) {
        __syncthreads();                          // prev-layer LDS reads done
        {
            const float4* g4 = (const float4*)(W_gc + (size_t)k * EMB * EMB);
            const float4* b4 = (const float4*)(W_bi + (size_t)k * EMB * EMB);
            float4* lg = (float4*)wg;
            float4* lb = (float4*)wb;
            #pragma unroll
            for (int i2 = tid; i2 < EMB * EMB / 4; i2 += 256) { lg[i2] = g4[i2]; lb[i2] = b4[i2]; }
        }
        __syncthreads();                          // weights ready

        float b1 = b_gc[k * EMB + j];
        float b2 = b_bi[k * EMB + j];
        float sum1[4], sum2[4], pv[4];
        #pragma unroll
        for (int s = 0; s < 4; ++s) { sum1[s] = b1; sum2[s] = b2; pv[s] = sval[s] * e[s]; }

        #pragma unroll 8
        for (int i = 0; i < EMB; ++i) {
            float wgi = wg[i * EMB + j];
            float wbi = wb[i * EMB + j];
            #pragma unroll
            for (int s = 0; s < 4; ++s) {
                float si = __uint_as_float(__builtin_amdgcn_readlane(__float_as_uint(sval[s]), i));
                float pi = __uint_as_float(__builtin_amdgcn_readlane(__float_as_uint(pv[s]),   i));
                sum1[s] = fmaf(si, wgi, sum1[s]);
                sum2[s] = fmaf(pi, wbi, sum2[s]);
            }
        }

        #pragma unroll
        for (int s = 0; s < 4; ++s) {
            float x = sum1[s] + sum2[s];
            x = (x >= 0.f) ? x : 0.2f * x;        // leaky_relu 0.2
            float sq = x * x;                     // wave-wide L2 norm
            #pragma unroll
            for (int o = 32; o; o >>= 1) sq += __shfl_xor(sq, o, 64);
            float nn = fmaxf(sqrtf(sq), 1e-12f);
            out[(size_t)(sbase + s) * 256 + (k + 1) * 64 + j] = x / nn;
            e[s] = x;                             // next-layer ego = unnormalized output
        }
    }
}

extern "C" void kernel_launch(void* const* d_in, const int* in_sizes, int n_in,
                              void* d_out, int out_size, void* d_ws, size_t ws_size,
                              hipStream_t stream) {
    const int*   users    = (const int*)  d_in[0];
    const int*   pos      = (const int*)  d_in[1];
    const int*   neg      = (const int*)  d_in[2];
    const int*   row      = (const int*)  d_in[3];
    const int*   col      = (const int*)  d_in[4];
    const float* vals     = (const float*)d_in[5];
    const float* user_emb = (const float*)d_in[6];
    const float* item_emb = (const float*)d_in[7];
    const float* W_gc     = (const float*)d_in[8];
    const float* b_gc     = (const float*)d_in[9];
    const float* W_bi     = (const float*)d_in[10];
    const float* b_bi     = (const float*)d_in[11];
    float* out = (float*)d_out;

    char* ws = (char*)d_ws;
    unsigned short* table16 = (unsigned short*)ws;
    int*            count   = (int*)(ws + 600064);
    int2*           csr2    = (int2*)(ws + 649216);
    float*          side    = (float*)(ws + 10086400);

    k_clear<<<(TBL4 + CNT4 + 255) / 256, 256, 0, stream>>>((int4*)table16, (int4*)count);
    k_setup<<<(NSLOT + 255) / 256, 256, 0, stream>>>(users, pos, neg, table16);
    k_build<<<(NNZ / 4 + 511) / 512, 256, 0, stream>>>(row, col, vals, table16,
                                                       count, csr2);
    k_gather<<<NSLOT / 4, 256, 0, stream>>>(users, pos, neg, user_emb, item_emb,
                                            table16, count, csr2, side);
    k_mlp<<<NSLOT / 16, 256, 0, stream>>>(users, pos, neg, user_emb, item_emb,
                                          W_gc, b_gc, W_bi, b_bi, side, out);
}